// Round 1
// baseline (166.528 us; speedup 1.0000x reference)
//
#include <hip/hip_runtime.h>
#include <hip/hip_bf16.h>

// Problem: b=16, n=2048, m=2048, d=128, dv=128, fp32 in/out, temp=sqrt(128).
// Strategy: preprocess to bf16 (Q pre-scaled by log2e/temp, V transposed),
// then flash attention with 32x32x16 bf16 MFMA, no-max online softmax.

#define BATCH 16
#define SEQ   2048
#define DIM   128

typedef short  bf16x8 __attribute__((ext_vector_type(8)));
typedef float  f32x16 __attribute__((ext_vector_type(16)));

static __device__ inline unsigned short f2bf(float f) {
  union { float f; unsigned u; } v; v.f = f;
  unsigned r = v.u + 0x7FFFu + ((v.u >> 16) & 1u);  // RNE
  return (unsigned short)(r >> 16);
}
static __device__ inline float bf2f(unsigned short s) {
  union { unsigned u; float f; } v; v.u = ((unsigned)s) << 16;
  return v.f;
}
static __device__ inline float fast_exp2(float x) {
#if __has_builtin(__builtin_amdgcn_exp2f)
  return __builtin_amdgcn_exp2f(x);
#else
  return exp2f(x);
#endif
}

// ---- preprocess: fp32 -> bf16 elementwise (with scale) ----
__global__ void cvt_kernel(const float* __restrict__ src,
                           unsigned short* __restrict__ dst, float scale) {
  int i = blockIdx.x * blockDim.x + threadIdx.x;  // one float4 per thread
  float4 a = ((const float4*)src)[i];
  ushort4 o;
  o.x = f2bf(a.x * scale); o.y = f2bf(a.y * scale);
  o.z = f2bf(a.z * scale); o.w = f2bf(a.w * scale);
  ((ushort4*)dst)[i] = o;
}

// ---- preprocess: V[b][m][dv] fp32 -> Vt[b][dv][m] bf16 ----
__global__ void vtrans_kernel(const float* __restrict__ V,
                              unsigned short* __restrict__ Vt) {
  __shared__ float tile[32][33];
  int b = blockIdx.z, m0 = blockIdx.x * 32, d0 = blockIdx.y * 32;
  int tx = threadIdx.x, ty = threadIdx.y;
  const float* src = V + ((size_t)(b * SEQ + m0)) * DIM + d0;
#pragma unroll
  for (int k = 0; k < 4; ++k)
    tile[ty + 8 * k][tx] = src[(ty + 8 * k) * DIM + tx];
  __syncthreads();
  unsigned short* dst = Vt + (size_t)b * SEQ * DIM + (size_t)d0 * SEQ + m0;
#pragma unroll
  for (int k = 0; k < 4; ++k)
    dst[(ty + 8 * k) * SEQ + tx] = f2bf(tile[tx][ty + 8 * k]);
}

// ---- main flash attention ----
// Block: 128 threads (2 waves). Wave w handles 32 q-rows. BQ=64, BK=64.
// Grid: (16 batches, 32 q-tiles) -> same-batch blocks share XCD (idx%8==batch%8).
#define BK 64
#define KS_STRIDE 136   // 128 + 8 ushorts  (pad: row shift = 4 banks)
#define VS_STRIDE 72    // 64 + 8
#define PS_STRIDE 72

__global__ __launch_bounds__(128, 2)
void attn_kernel(const unsigned short* __restrict__ Qb,
                 const unsigned short* __restrict__ Kb,
                 const unsigned short* __restrict__ Vtb,
                 float* __restrict__ out) {
  __shared__ unsigned short Ks[64 * KS_STRIDE];    // K-tile  [kk][d]
  __shared__ unsigned short Vs[128 * VS_STRIDE];   // Vt-tile [dv][kk]
  __shared__ unsigned short Ps[2 * 32 * PS_STRIDE];// P per wave [q][kk]

  const int tid  = threadIdx.x;
  const int wv   = tid >> 6;
  const int lane = tid & 63;
  const int l31  = lane & 31;
  const int q2   = lane >> 5;          // half-wave index
  const int b    = blockIdx.x;
  const int q0   = blockIdx.y * 64 + wv * 32;   // this wave's first q row

  // Q fragments: A[m=l31][k = c*16 + q2*8 + j], held in registers for the block
  bf16x8 aq[8];
  {
    const unsigned short* qptr =
        Qb + ((size_t)(b * SEQ + q0 + l31)) * DIM + q2 * 8;
#pragma unroll
    for (int c = 0; c < 8; ++c)
      aq[c] = *(const bf16x8*)(qptr + c * 16);
  }

  f32x16 oacc[4];
#pragma unroll
  for (int t = 0; t < 4; ++t)
#pragma unroll
    for (int i = 0; i < 16; ++i) oacc[t][i] = 0.0f;
  float lsum[16];
#pragma unroll
  for (int i = 0; i < 16; ++i) lsum[i] = 0.0f;

  const unsigned short* kbase = Kb  + (size_t)b * SEQ * DIM;  // [m][d]
  const unsigned short* vbase = Vtb + (size_t)b * SEQ * DIM;  // [dv][m]

  for (int kt = 0; kt < SEQ / BK; ++kt) {
    const int m0 = kt * BK;
    __syncthreads();  // previous iteration's LDS reads complete
    // stage K-tile: 64 rows x 16 chunks of 16B
#pragma unroll
    for (int i = 0; i < 8; ++i) {
      int idx = i * 128 + tid;
      int row = idx >> 4, c = idx & 15;
      uint4 v = *(const uint4*)(kbase + (m0 + row) * DIM + c * 8);
      *(uint4*)(&Ks[row * KS_STRIDE + c * 8]) = v;
    }
    // stage Vt-tile: 128 rows x 8 chunks of 16B
#pragma unroll
    for (int i = 0; i < 8; ++i) {
      int idx = i * 128 + tid;
      int dv = idx >> 3, c = idx & 7;
      uint4 v = *(const uint4*)(vbase + (size_t)dv * SEQ + m0 + c * 8);
      *(uint4*)(&Vs[dv * VS_STRIDE + c * 8]) = v;
    }
    __syncthreads();

    // S = Q * K^T  (already in log2 domain via Q pre-scale)
    f32x16 sacc[2];
#pragma unroll
    for (int t = 0; t < 2; ++t)
#pragma unroll
      for (int i = 0; i < 16; ++i) sacc[t][i] = 0.0f;
#pragma unroll
    for (int c = 0; c < 8; ++c) {
#pragma unroll
      for (int t = 0; t < 2; ++t) {
        bf16x8 bk = *(const bf16x8*)(&Ks[(t * 32 + l31) * KS_STRIDE + c * 16 + q2 * 8]);
        sacc[t] = __builtin_amdgcn_mfma_f32_32x32x16_bf16(aq[c], bk, sacc[t], 0, 0, 0);
      }
    }

    // P = exp2(S); accumulate row sums; stage P (bf16) to LDS in C-layout
#pragma unroll
    for (int t = 0; t < 2; ++t) {
#pragma unroll
      for (int r = 0; r < 16; ++r) {
        float p = fast_exp2(sacc[t][r]);
        unsigned short pb = f2bf(p);
        lsum[r] += bf2f(pb);  // keep numerator/denominator consistent
        int row = (r & 3) + ((r >> 2) << 3) + q2 * 4;
        Ps[(wv * 32 + row) * PS_STRIDE + t * 32 + l31] = pb;
      }
    }
    __syncthreads();  // P visible (and cross-wave point for staging order)

    // O += P * V   A[m=q][k=kk] from Ps, B[k=kk][n=dv] from Vs
    bf16x8 pf[4];
#pragma unroll
    for (int c = 0; c < 4; ++c)
      pf[c] = *(const bf16x8*)(&Ps[(wv * 32 + l31) * PS_STRIDE + c * 16 + q2 * 8]);
#pragma unroll
    for (int c = 0; c < 4; ++c) {
#pragma unroll
      for (int t = 0; t < 4; ++t) {
        bf16x8 bv = *(const bf16x8*)(&Vs[(t * 32 + l31) * VS_STRIDE + c * 16 + q2 * 8]);
        oacc[t] = __builtin_amdgcn_mfma_f32_32x32x16_bf16(pf[c], bv, oacc[t], 0, 0, 0);
      }
    }
  }

  // reduce row sums across the 32 lanes of each half-wave
#pragma unroll
  for (int r = 0; r < 16; ++r) {
    float s = lsum[r];
#pragma unroll
    for (int m = 1; m < 32; m <<= 1) s += __shfl_xor(s, m, 64);
    lsum[r] = 1.0f / s;
  }

  // epilogue: normalize and store fp32
  float* obase = out + ((size_t)(b * SEQ + q0)) * DIM;
#pragma unroll
  for (int t = 0; t < 4; ++t) {
#pragma unroll
    for (int r = 0; r < 16; ++r) {
      int row = (r & 3) + ((r >> 2) << 3) + q2 * 4;
      obase[row * DIM + t * 32 + l31] = oacc[t][r] * lsum[r];
    }
  }
}

extern "C" void kernel_launch(void* const* d_in, const int* in_sizes, int n_in,
                              void* d_out, int out_size, void* d_ws, size_t ws_size,
                              hipStream_t stream) {
  const float* Q = (const float*)d_in[0];
  const float* K = (const float*)d_in[1];
  const float* V = (const float*)d_in[2];
  float* out = (float*)d_out;

  const size_t elems = (size_t)BATCH * SEQ * DIM;      // 4,194,304
  unsigned short* Qb = (unsigned short*)d_ws;          // 8 MB
  unsigned short* Kb = Qb + elems;                     // 8 MB
  unsigned short* Vt = Kb + elems;                     // 8 MB  (needs ws >= 24 MB)

  const float TEMPERATURE = 11.313708498984761f;
  const float qscale = 1.4426950408889634f / TEMPERATURE;  // fold log2(e)

  int n4 = (int)(elems / 4);
  cvt_kernel<<<n4 / 256, 256, 0, stream>>>(Q, Qb, qscale);
  cvt_kernel<<<n4 / 256, 256, 0, stream>>>(K, Kb, 1.0f);
  vtrans_kernel<<<dim3(SEQ / 32, DIM / 32, BATCH), dim3(32, 8), 0, stream>>>(V, Vt);
  attn_kernel<<<dim3(BATCH, SEQ / 64), 128, 0, stream>>>(Qb, Kb, Vt, out);
}